// Round 8
// baseline (323.815 us; speedup 1.0000x reference)
//
#include <hip/hip_runtime.h>
#include <math.h>

#define NVEC 32768   // 32*32*32 vectors
#define NE   1024    // codebook entries
#define ED   64      // embedding dim
#define TOT  2097152 // NVEC*ED total z elements
#define NCHUNK 8     // code chunks in k_dist
#define CHUNK  128   // codes per chunk

// d_out offsets (in floats): loss | z_q_st | perplexity | min_encodings | idx
#define O_LOSS   0
#define O_ZQ     1
#define O_PERP   2097153
#define O_MINENC 2097154
#define O_IDX    35651586

// d_ws offsets (in floats). No ws memset: every cell read has a producer.
#define W_PDIST  0        // [8][32768] chunk best d
#define W_PIDX   262144   // [8][32768] chunk best idx (int); chunk-0 slot -> final idx
#define W_CS     524288   // [1024]
#define W_SUMENC 525312   // [1024*64]
#define W_NEWEMB 590848   // [1024*64]
#define W_LOSSP  656384   // [2048]

// numpy pairwise sum (n=64, contiguous path): 8 accumulators r[j] += x[8i+j],
// combined ((r0+r1)+(r2+r3))+((r4+r5)+(r6+r7)). All ops forced IEEE fp32.
__device__ __forceinline__ float np_pairwise64_sq(const float* v) {
    float r[8];
#pragma unroll
    for (int j = 0; j < 8; ++j) r[j] = __fmul_rn(v[j], v[j]);
#pragma unroll
    for (int i = 8; i < 64; i += 8) {
#pragma unroll
        for (int j = 0; j < 8; ++j)
            r[j] = __fadd_rn(r[j], __fmul_rn(v[i + j], v[i + j]));
    }
    return __fadd_rn(
        __fadd_rn(__fadd_rn(r[0], r[1]), __fadd_rn(r[2], r[3])),
        __fadd_rn(__fadd_rn(r[4], r[5]), __fadd_rn(r[6], r[7])));
}

// grid (128 vec-tiles, 8 code-chunks), block 256, launch_bounds(256,4) -> <=128 VGPR.
// R7 post-mortem: compiler reported VGPR=40 — it sank the zv loads into the kk
// loop (re-reading z from L2 every iteration) instead of keeping zv register-
// resident. Fix: asm "+v" pin after the exact x2 — forces 64 VGPRs for zv and
// blocks load rematerialization. Numerics identical to R7 (passed).
__global__ void __launch_bounds__(256, 4) k_dist(const float* __restrict__ z,
                                                 const float* __restrict__ emb,
                                                 float* __restrict__ pdist,
                                                 int* __restrict__ pidx) {
    __shared__ float s_esq[CHUNK];
    int k0 = blockIdx.y * CHUNK;
    if (threadIdx.x < CHUNK) {
        int k = k0 + threadIdx.x;
        float e[ED];
#pragma unroll
        for (int c = 0; c < ED; ++c) e[c] = emb[k * ED + c];
        s_esq[threadIdx.x] = np_pairwise64_sq(e);
    }
    __syncthreads();

    int n = blockIdx.x * 256 + threadIdx.x;
    int b = n >> 10, hw = n & 1023;
    const float* zp = z + b * 65536 + hw;  // element c at zp[c*1024]
    float zv[ED];
#pragma unroll
    for (int c = 0; c < ED; ++c) zv[c] = zp[c << 10];

    float zsq = np_pairwise64_sq(zv);  // np.sum(zf*zf, axis=1) bit pattern

#pragma unroll
    for (int c = 0; c < ED; ++c) zv[c] = __fmul_rn(2.0f, zv[c]);  // (2.0*zf), exact

    // Pin the doubled z vector into VGPRs: "+v" demands a register and makes the
    // value opaque, so the scheduler can't sink/remat the global loads into the loop.
#pragma unroll
    for (int c = 0; c < ED; ++c) asm volatile("" : "+v"(zv[c]));

    float best = 3.4e38f;
    int bi = k0;
    for (int kk = 0; kk < CHUNK; kk += 2) {
        const float4* ep0 = (const float4*)(emb + (size_t)(k0 + kk) * ED);
        const float4* ep1 = ep0 + 16;
        float a0 = 0.f, a1 = 0.f;  // two sequential chains, independent of each other
#pragma unroll
        for (int j = 0; j < 16; ++j) {
            float4 e0 = ep0[j];
            float4 e1 = ep1[j];
            a0 = __fmaf_rn(zv[4 * j + 0], e0.x, a0);
            a1 = __fmaf_rn(zv[4 * j + 0], e1.x, a1);
            a0 = __fmaf_rn(zv[4 * j + 1], e0.y, a0);
            a1 = __fmaf_rn(zv[4 * j + 1], e1.y, a1);
            a0 = __fmaf_rn(zv[4 * j + 2], e0.z, a0);
            a1 = __fmaf_rn(zv[4 * j + 2], e1.z, a1);
            a0 = __fmaf_rn(zv[4 * j + 3], e0.w, a0);
            a1 = __fmaf_rn(zv[4 * j + 3], e1.w, a1);
        }
        float d0 = __fsub_rn(__fadd_rn(zsq, s_esq[kk]), a0);
        float d1 = __fsub_rn(__fadd_rn(zsq, s_esq[kk + 1]), a1);
        if (d0 < best) { best = d0; bi = k0 + kk; }      // ascending k, strict <
        if (d1 < best) { best = d1; bi = k0 + kk + 1; }  // -> np first-index ties
    }
    pdist[blockIdx.y * NVEC + n] = best;
    pidx[blockIdx.y * NVEC + n] = bi;
}

// Merge 8 chunks (ascending -> first-index ties); write idx; write FULL one-hot
// rows cooperatively (replaces the 134 MB memset; coalesced float2 stores —
// O_MINENC is 8B- but not 16B-aligned).
__global__ void __launch_bounds__(256) k_combine(const float* __restrict__ pdist,
                                                 int* __restrict__ pidx,
                                                 float* __restrict__ out) {
    __shared__ int sbi[256];
    int n = blockIdx.x * 256 + threadIdx.x;
    float best = pdist[n];
    int bi = pidx[n];
#pragma unroll
    for (int q = 1; q < NCHUNK; ++q) {
        float d = pdist[q * NVEC + n];
        int i = pidx[q * NVEC + n];
        if (d < best) { best = d; bi = i; }
    }
    pidx[n] = bi;  // final idx (own slot only)
    out[O_IDX + n] = (float)bi;
    sbi[threadIdx.x] = bi;
    __syncthreads();
    int wave = threadIdx.x >> 6, lane = threadIdx.x & 63;
    size_t base = (size_t)O_MINENC + (size_t)blockIdx.x * 256 * NE;
    for (int r = wave; r < 256; r += 4) {
        int rbi = sbi[r];
        float* rp = out + base + (size_t)r * NE;
#pragma unroll
        for (int s = 0; s < 8; ++s) {
            int col = s * 128 + lane * 2;
            float2 v;
            v.x = (col == rbi) ? 1.0f : 0.0f;
            v.y = (col + 1 == rbi) ? 1.0f : 0.0f;
            *(float2*)(rp + col) = v;
        }
    }
}

// Gather-based segment sum: one block per code k, 4 waves. Ballot-scan idx;
// members accumulated lane=element; popcount -> cs. Deterministic. No atomics.
__global__ void __launch_bounds__(256) k_sumenc(const int* __restrict__ idx,
                                                const float* __restrict__ z,
                                                float* __restrict__ cs,
                                                float* __restrict__ sumenc) {
    int k = blockIdx.x;
    int wave = threadIdx.x >> 6, lane = threadIdx.x & 63;
    float acc = 0.f;
    int cnt = 0;
    int base = wave * 8192;
    for (int it = 0; it < 128; ++it) {
        int n0 = base + it * 64;
        int idv = idx[n0 + lane];
        unsigned long long m = __ballot(idv == k);
        cnt += __popcll(m);
        while (m) {
            int bit = __ffsll((unsigned long long)m) - 1;  // ascending n
            m &= m - 1;
            int n = n0 + bit;
            int b = n >> 10, hw = n & 1023;
            acc = __fadd_rn(acc, z[b * 65536 + lane * 1024 + hw]);  // element c = lane
        }
    }
    __shared__ float sacc[4][64];
    __shared__ int scnt[4];
    sacc[wave][lane] = acc;
    if (lane == 0) scnt[wave] = cnt;
    __syncthreads();
    if (wave == 0) {
        float t = __fadd_rn(__fadd_rn(sacc[0][lane], sacc[1][lane]),
                            __fadd_rn(sacc[2][lane], sacc[3][lane]));
        sumenc[k * ED + lane] = t;
        if (lane == 0) cs[k] = (float)(scnt[0] + scnt[1] + scnt[2] + scnt[3]);
    }
}

// Single block, 1024 threads: EMA cluster-size + ntot/entropy reductions +
// perplexity + codebook update. Fused.
__global__ void __launch_bounds__(1024) k_ema(const float* __restrict__ ema_cs,
                                              const float* __restrict__ ema_w,
                                              const float* __restrict__ cs,
                                              const float* __restrict__ sumenc,
                                              float* __restrict__ newemb,
                                              float* __restrict__ out) {
    int k = threadIdx.x;  // 0..1023 == NE
    float c = cs[k];
    float ncs = 0.99f * ema_cs[k] + (1.0f - 0.99f) * c;
    float p = c * (1.0f / (float)NVEC);
    float e = p * logf(p + 1e-10f);
    float rn_ = ncs, re_ = e;
#pragma unroll
    for (int o = 32; o > 0; o >>= 1) {
        rn_ += __shfl_down(rn_, o, 64);
        re_ += __shfl_down(re_, o, 64);
    }
    __shared__ float sn[16], se_[16];
    __shared__ float s_n;
    int wave = k >> 6, lane = k & 63;
    if (lane == 0) { sn[wave] = rn_; se_[wave] = re_; }
    __syncthreads();
    if (k == 0) {
        float tn = 0.f, te = 0.f;
#pragma unroll
        for (int w = 0; w < 16; ++w) { tn += sn[w]; te += se_[w]; }
        s_n = tn;
        out[O_PERP] = expf(-te);
    }
    __syncthreads();
    float nt = s_n;
    float csn = (ncs + 1e-5f) / (nt + 1024.0f * 1e-5f) * nt;
    __shared__ float s_csn[NE];
    s_csn[k] = csn;
    __syncthreads();
    for (int t = k; t < NE * ED; t += 1024) {  // coalesced
        float nw = 0.99f * ema_w[t] + (1.0f - 0.99f) * sumenc[t];
        newemb[t] = nw / s_csn[t >> 6];
    }
}

// 2048 blocks x 256 threads x 4 elems. Per-block partial loss, one plain store.
__global__ void __launch_bounds__(256) k_zq(const float* __restrict__ z,
                                            const int* __restrict__ idx,
                                            const float* __restrict__ newemb,
                                            float* __restrict__ out,
                                            float* __restrict__ lossp) {
    float local = 0.f;
#pragma unroll
    for (int i = 0; i < 4; ++i) {
        int t = blockIdx.x * 256 + threadIdx.x + i * 524288;
        int b = t >> 16, c = (t >> 10) & 63, hw = t & 1023;
        int n = (b << 10) | hw;
        float e = newemb[idx[n] * ED + c];
        float zv = z[t];
        float diff = e - zv;             // z_q - z
        out[O_ZQ + t] = zv + diff;       // straight-through: z + (z_q - z)
        local = fmaf(diff, diff, local);
    }
#pragma unroll
    for (int o = 32; o > 0; o >>= 1) local += __shfl_down(local, o, 64);
    __shared__ float sp[4];
    int wave = threadIdx.x >> 6;
    if ((threadIdx.x & 63) == 0) sp[wave] = local;
    __syncthreads();
    if (threadIdx.x == 0)
        lossp[blockIdx.x] = (sp[0] + sp[1]) + (sp[2] + sp[3]);
}

// One block, 256 threads: reduce 2048 partials -> loss.
__global__ void __launch_bounds__(256) k_fin(const float* __restrict__ lossp,
                                             float* __restrict__ out) {
    float v = 0.f;
#pragma unroll
    for (int i = 0; i < 8; ++i) v += lossp[i * 256 + threadIdx.x];
#pragma unroll
    for (int o = 32; o > 0; o >>= 1) v += __shfl_down(v, o, 64);
    __shared__ float sp[4];
    int wave = threadIdx.x >> 6;
    if ((threadIdx.x & 63) == 0) sp[wave] = v;
    __syncthreads();
    if (threadIdx.x == 0)
        out[O_LOSS] = 0.25f * (((sp[0] + sp[1]) + (sp[2] + sp[3])) * (1.0f / (float)TOT));
}

extern "C" void kernel_launch(void* const* d_in, const int* in_sizes, int n_in,
                              void* d_out, int out_size, void* d_ws, size_t ws_size,
                              hipStream_t stream) {
    const float* z      = (const float*)d_in[0];
    const float* emb    = (const float*)d_in[1];
    const float* ema_cs = (const float*)d_in[2];
    const float* ema_w  = (const float*)d_in[3];
    float* out = (float*)d_out;
    float* ws  = (float*)d_ws;

    k_dist<<<dim3(128, NCHUNK), 256, 0, stream>>>(z, emb, ws + W_PDIST,
                                                  (int*)(ws + W_PIDX));
    k_combine<<<128, 256, 0, stream>>>(ws + W_PDIST, (int*)(ws + W_PIDX), out);
    k_sumenc<<<NE, 256, 0, stream>>>((const int*)(ws + W_PIDX), z, ws + W_CS,
                                     ws + W_SUMENC);
    k_ema<<<1, 1024, 0, stream>>>(ema_cs, ema_w, ws + W_CS, ws + W_SUMENC,
                                  ws + W_NEWEMB, out);
    k_zq<<<2048, 256, 0, stream>>>(z, (const int*)(ws + W_PIDX), ws + W_NEWEMB, out,
                                   ws + W_LOSSP);
    k_fin<<<1, 256, 0, stream>>>(ws + W_LOSSP, out);
}

// Round 9
// 318.515 us; speedup vs baseline: 1.0166x; 1.0166x over previous
//
#include <hip/hip_runtime.h>
#include <math.h>

#define NVEC 32768   // 32*32*32 vectors
#define NE   1024    // codebook entries
#define ED   64      // embedding dim
#define TOT  2097152 // NVEC*ED total z elements
#define NCHUNK 8     // code chunks in k_dist
#define CHUNK  128   // codes per chunk

// d_out offsets (in floats): loss | z_q_st | perplexity | min_encodings | idx
#define O_LOSS   0
#define O_ZQ     1
#define O_PERP   2097153
#define O_MINENC 2097154
#define O_IDX    35651586

// d_ws offsets (in floats). No ws memset: every cell read has a producer.
#define W_PDIST  0        // [8][32768] chunk best d
#define W_PIDX   262144   // [8][32768] chunk best idx (int); chunk-0 slot -> final idx
#define W_CS     524288   // [1024]
#define W_SUMENC 525312   // [1024*64]
#define W_NEWEMB 590848   // [1024*64]
#define W_LOSSP  656384   // [2048]

// numpy pairwise sum (n=64, contiguous path): 8 accumulators r[j] += x[8i+j],
// combined ((r0+r1)+(r2+r3))+((r4+r5)+(r6+r7)). All ops forced IEEE fp32.
__device__ __forceinline__ float np_pairwise64_sq(const float* v) {
    float r[8];
#pragma unroll
    for (int j = 0; j < 8; ++j) r[j] = __fmul_rn(v[j], v[j]);
#pragma unroll
    for (int i = 8; i < 64; i += 8) {
#pragma unroll
        for (int j = 0; j < 8; ++j)
            r[j] = __fadd_rn(r[j], __fmul_rn(v[i + j], v[i + j]));
    }
    return __fadd_rn(
        __fadd_rn(__fadd_rn(r[0], r[1]), __fadd_rn(r[2], r[3])),
        __fadd_rn(__fadd_rn(r[4], r[5]), __fadd_rn(r[6], r[7])));
}

// grid (128 vec-tiles, 8 code-chunks), block 256.
// R8 post-mortem: launch_bounds(256,4) sets only a MIN waves/EU — the allocator
// still targeted 8 waves/EU (VGPR=40) and re-read z from L2 every kk iteration
// (~4.3 GB L2 traffic ≈ the whole 102 µs). amdgpu_waves_per_eu(4,4) pins the
// occupancy target: 128-VGPR budget, no incentive to sink the zv loads.
// Grid is exactly 4 blocks/CU x 4 waves = 4 waves/EU, so nothing is lost.
__global__ __attribute__((amdgpu_waves_per_eu(4, 4))) void __launch_bounds__(256)
k_dist(const float* __restrict__ z,
       const float* __restrict__ emb,
       float* __restrict__ pdist,
       int* __restrict__ pidx) {
    __shared__ float s_esq[CHUNK];
    int k0 = blockIdx.y * CHUNK;
    if (threadIdx.x < CHUNK) {
        int k = k0 + threadIdx.x;
        float e[ED];
#pragma unroll
        for (int c = 0; c < ED; ++c) e[c] = emb[k * ED + c];
        s_esq[threadIdx.x] = np_pairwise64_sq(e);
    }
    __syncthreads();

    int n = blockIdx.x * 256 + threadIdx.x;
    int b = n >> 10, hw = n & 1023;
    const float* zp = z + b * 65536 + hw;  // element c at zp[c*1024]
    float zv[ED];
#pragma unroll
    for (int c = 0; c < ED; ++c) zv[c] = zp[c << 10];

    float zsq = np_pairwise64_sq(zv);  // np.sum(zf*zf, axis=1) bit pattern

#pragma unroll
    for (int c = 0; c < ED; ++c) zv[c] = __fmul_rn(2.0f, zv[c]);  // (2.0*zf), exact

    // Pin the doubled z vector into VGPRs (opaque to remat/sinking).
#pragma unroll
    for (int c = 0; c < ED; ++c) asm volatile("" : "+v"(zv[c]));

    float best = 3.4e38f;
    int bi = k0;
    for (int kk = 0; kk < CHUNK; kk += 2) {
        const float4* ep0 = (const float4*)(emb + (size_t)(k0 + kk) * ED);
        const float4* ep1 = ep0 + 16;
        float a0 = 0.f, a1 = 0.f;  // two sequential chains, independent of each other
#pragma unroll
        for (int j = 0; j < 16; ++j) {
            float4 e0 = ep0[j];
            float4 e1 = ep1[j];
            a0 = __fmaf_rn(zv[4 * j + 0], e0.x, a0);
            a1 = __fmaf_rn(zv[4 * j + 0], e1.x, a1);
            a0 = __fmaf_rn(zv[4 * j + 1], e0.y, a0);
            a1 = __fmaf_rn(zv[4 * j + 1], e1.y, a1);
            a0 = __fmaf_rn(zv[4 * j + 2], e0.z, a0);
            a1 = __fmaf_rn(zv[4 * j + 2], e1.z, a1);
            a0 = __fmaf_rn(zv[4 * j + 3], e0.w, a0);
            a1 = __fmaf_rn(zv[4 * j + 3], e1.w, a1);
        }
        float d0 = __fsub_rn(__fadd_rn(zsq, s_esq[kk]), a0);
        float d1 = __fsub_rn(__fadd_rn(zsq, s_esq[kk + 1]), a1);
        if (d0 < best) { best = d0; bi = k0 + kk; }      // ascending k, strict <
        if (d1 < best) { best = d1; bi = k0 + kk + 1; }  // -> np first-index ties
    }
    pdist[blockIdx.y * NVEC + n] = best;
    pidx[blockIdx.y * NVEC + n] = bi;
}

// Merge 8 chunks (ascending -> first-index ties); write idx; write FULL one-hot
// rows cooperatively (replaces the 134 MB memset; coalesced float2 stores —
// O_MINENC is 8B- but not 16B-aligned).
__global__ void __launch_bounds__(256) k_combine(const float* __restrict__ pdist,
                                                 int* __restrict__ pidx,
                                                 float* __restrict__ out) {
    __shared__ int sbi[256];
    int n = blockIdx.x * 256 + threadIdx.x;
    float best = pdist[n];
    int bi = pidx[n];
#pragma unroll
    for (int q = 1; q < NCHUNK; ++q) {
        float d = pdist[q * NVEC + n];
        int i = pidx[q * NVEC + n];
        if (d < best) { best = d; bi = i; }
    }
    pidx[n] = bi;  // final idx (own slot only)
    out[O_IDX + n] = (float)bi;
    sbi[threadIdx.x] = bi;
    __syncthreads();
    int wave = threadIdx.x >> 6, lane = threadIdx.x & 63;
    size_t base = (size_t)O_MINENC + (size_t)blockIdx.x * 256 * NE;
    for (int r = wave; r < 256; r += 4) {
        int rbi = sbi[r];
        float* rp = out + base + (size_t)r * NE;
#pragma unroll
        for (int s = 0; s < 8; ++s) {
            int col = s * 128 + lane * 2;
            float2 v;
            v.x = (col == rbi) ? 1.0f : 0.0f;
            v.y = (col + 1 == rbi) ? 1.0f : 0.0f;
            *(float2*)(rp + col) = v;
        }
    }
}

// Gather-based segment sum: one block per code k, 4 waves. Ballot-scan idx;
// members accumulated lane=element; popcount -> cs. Deterministic. No atomics.
__global__ void __launch_bounds__(256) k_sumenc(const int* __restrict__ idx,
                                                const float* __restrict__ z,
                                                float* __restrict__ cs,
                                                float* __restrict__ sumenc) {
    int k = blockIdx.x;
    int wave = threadIdx.x >> 6, lane = threadIdx.x & 63;
    float acc = 0.f;
    int cnt = 0;
    int base = wave * 8192;
    for (int it = 0; it < 128; ++it) {
        int n0 = base + it * 64;
        int idv = idx[n0 + lane];
        unsigned long long m = __ballot(idv == k);
        cnt += __popcll(m);
        while (m) {
            int bit = __ffsll((unsigned long long)m) - 1;  // ascending n
            m &= m - 1;
            int n = n0 + bit;
            int b = n >> 10, hw = n & 1023;
            acc = __fadd_rn(acc, z[b * 65536 + lane * 1024 + hw]);  // element c = lane
        }
    }
    __shared__ float sacc[4][64];
    __shared__ int scnt[4];
    sacc[wave][lane] = acc;
    if (lane == 0) scnt[wave] = cnt;
    __syncthreads();
    if (wave == 0) {
        float t = __fadd_rn(__fadd_rn(sacc[0][lane], sacc[1][lane]),
                            __fadd_rn(sacc[2][lane], sacc[3][lane]));
        sumenc[k * ED + lane] = t;
        if (lane == 0) cs[k] = (float)(scnt[0] + scnt[1] + scnt[2] + scnt[3]);
    }
}

// Single block, 1024 threads: EMA cluster-size + ntot/entropy reductions +
// perplexity + codebook update. Fused.
__global__ void __launch_bounds__(1024) k_ema(const float* __restrict__ ema_cs,
                                              const float* __restrict__ ema_w,
                                              const float* __restrict__ cs,
                                              const float* __restrict__ sumenc,
                                              float* __restrict__ newemb,
                                              float* __restrict__ out) {
    int k = threadIdx.x;  // 0..1023 == NE
    float c = cs[k];
    float ncs = 0.99f * ema_cs[k] + (1.0f - 0.99f) * c;
    float p = c * (1.0f / (float)NVEC);
    float e = p * logf(p + 1e-10f);
    float rn_ = ncs, re_ = e;
#pragma unroll
    for (int o = 32; o > 0; o >>= 1) {
        rn_ += __shfl_down(rn_, o, 64);
        re_ += __shfl_down(re_, o, 64);
    }
    __shared__ float sn[16], se_[16];
    __shared__ float s_n;
    int wave = k >> 6, lane = k & 63;
    if (lane == 0) { sn[wave] = rn_; se_[wave] = re_; }
    __syncthreads();
    if (k == 0) {
        float tn = 0.f, te = 0.f;
#pragma unroll
        for (int w = 0; w < 16; ++w) { tn += sn[w]; te += se_[w]; }
        s_n = tn;
        out[O_PERP] = expf(-te);
    }
    __syncthreads();
    float nt = s_n;
    float csn = (ncs + 1e-5f) / (nt + 1024.0f * 1e-5f) * nt;
    __shared__ float s_csn[NE];
    s_csn[k] = csn;
    __syncthreads();
    for (int t = k; t < NE * ED; t += 1024) {  // coalesced
        float nw = 0.99f * ema_w[t] + (1.0f - 0.99f) * sumenc[t];
        newemb[t] = nw / s_csn[t >> 6];
    }
}

// 2048 blocks x 256 threads x 4 elems. Per-block partial loss, one plain store.
__global__ void __launch_bounds__(256) k_zq(const float* __restrict__ z,
                                            const int* __restrict__ idx,
                                            const float* __restrict__ newemb,
                                            float* __restrict__ out,
                                            float* __restrict__ lossp) {
    float local = 0.f;
#pragma unroll
    for (int i = 0; i < 4; ++i) {
        int t = blockIdx.x * 256 + threadIdx.x + i * 524288;
        int b = t >> 16, c = (t >> 10) & 63, hw = t & 1023;
        int n = (b << 10) | hw;
        float e = newemb[idx[n] * ED + c];
        float zv = z[t];
        float diff = e - zv;             // z_q - z
        out[O_ZQ + t] = zv + diff;       // straight-through: z + (z_q - z)
        local = fmaf(diff, diff, local);
    }
#pragma unroll
    for (int o = 32; o > 0; o >>= 1) local += __shfl_down(local, o, 64);
    __shared__ float sp[4];
    int wave = threadIdx.x >> 6;
    if ((threadIdx.x & 63) == 0) sp[wave] = local;
    __syncthreads();
    if (threadIdx.x == 0)
        lossp[blockIdx.x] = (sp[0] + sp[1]) + (sp[2] + sp[3]);
}

// One block, 256 threads: reduce 2048 partials -> loss.
__global__ void __launch_bounds__(256) k_fin(const float* __restrict__ lossp,
                                             float* __restrict__ out) {
    float v = 0.f;
#pragma unroll
    for (int i = 0; i < 8; ++i) v += lossp[i * 256 + threadIdx.x];
#pragma unroll
    for (int o = 32; o > 0; o >>= 1) v += __shfl_down(v, o, 64);
    __shared__ float sp[4];
    int wave = threadIdx.x >> 6;
    if ((threadIdx.x & 63) == 0) sp[wave] = v;
    __syncthreads();
    if (threadIdx.x == 0)
        out[O_LOSS] = 0.25f * (((sp[0] + sp[1]) + (sp[2] + sp[3])) * (1.0f / (float)TOT));
}

extern "C" void kernel_launch(void* const* d_in, const int* in_sizes, int n_in,
                              void* d_out, int out_size, void* d_ws, size_t ws_size,
                              hipStream_t stream) {
    const float* z      = (const float*)d_in[0];
    const float* emb    = (const float*)d_in[1];
    const float* ema_cs = (const float*)d_in[2];
    const float* ema_w  = (const float*)d_in[3];
    float* out = (float*)d_out;
    float* ws  = (float*)d_ws;

    k_dist<<<dim3(128, NCHUNK), 256, 0, stream>>>(z, emb, ws + W_PDIST,
                                                  (int*)(ws + W_PIDX));
    k_combine<<<128, 256, 0, stream>>>(ws + W_PDIST, (int*)(ws + W_PIDX), out);
    k_sumenc<<<NE, 256, 0, stream>>>((const int*)(ws + W_PIDX), z, ws + W_CS,
                                     ws + W_SUMENC);
    k_ema<<<1, 1024, 0, stream>>>(ema_cs, ema_w, ws + W_CS, ws + W_SUMENC,
                                  ws + W_NEWEMB, out);
    k_zq<<<2048, 256, 0, stream>>>(z, (const int*)(ws + W_PIDX), ws + W_NEWEMB, out,
                                   ws + W_LOSSP);
    k_fin<<<1, 256, 0, stream>>>(ws + W_LOSSP, out);
}